// Round 3
// baseline (149.855 us; speedup 1.0000x reference)
//
#include <hip/hip_runtime.h>
#include <math.h>

#define NN 8
#define CC 20
#define PP 8732
#define MM 16
#define NPR 3
#define SPLIT 8
#define CH 1092              // ceil(PP/SPLIT)
#define ROWS (NN * CC)

__device__ __forceinline__ float fast_rcp(float x) { return __builtin_amdgcn_rcpf(x); }

// lse over 2 logits: mx + log(1 + exp(-|a-b|))  (1 exp + 1 log)
__device__ __forceinline__ float lse2(float a, float b) {
    float mx = fmaxf(a, b);
    float d  = fabsf(a - b);
    return mx + logf(1.0f + expf(-d));
}

// ---------------- Kernel A: IoU matching + ce + pre-force stats ----------------
#define ABLK 256
__global__ __launch_bounds__(ABLK) void mbox_p1(
    const float* __restrict__ locs, const float* __restrict__ scores,
    const float* __restrict__ boxes, const int* __restrict__ labels,
    const float* __restrict__ priors,
    unsigned char* __restrict__ pk8, float* __restrict__ ce0,
    unsigned long long* __restrict__ partials, float* __restrict__ cstats)
{
    const int row = blockIdx.x >> 3;      // SPLIT = 8
    const int chunk = blockIdx.x & 7;
    const int tid = threadIdx.x, lane = tid & 63, wav = tid >> 6;
    __shared__ float s_bx1[MM], s_by1[MM], s_bx2[MM], s_by2[MM], s_area[MM];
    __shared__ float s_bcx[MM], s_bcy[MM], s_bw[MM], s_bh[MM];
    __shared__ int s_lab[MM];
    __shared__ unsigned long long s_pk[4 * MM];
    __shared__ float s_rf[4 * 3];

    if (tid < MM) {
        const float* b = boxes + ((size_t)row * MM + tid) * 4;
        float x1 = b[0], y1 = b[1], x2 = b[2], y2 = b[3];
        s_bx1[tid] = x1; s_by1[tid] = y1; s_bx2[tid] = x2; s_by2[tid] = y2;
        s_area[tid] = (x2 - x1) * (y2 - y1);
        s_bcx[tid] = (x1 + x2) * 0.5f; s_bcy[tid] = (y1 + y2) * 0.5f;
        s_bw[tid] = x2 - x1; s_bh[tid] = y2 - y1;
        s_lab[tid] = labels[row * MM + tid];
    }
    __syncthreads();

    const float4* pri4 = (const float4*)priors;
    const float4* loc4 = (const float4*)(locs + (size_t)row * PP * 4);
    const float2* sc2  = (const float2*)(scores + (size_t)row * PP * 2);
    unsigned char* pk  = pk8 + (size_t)row * PP;
    float* cer         = ce0 + (size_t)row * PP;

    float bestv[MM]; int bestp[MM];
#pragma unroll
    for (int m = 0; m < MM; m++) { bestv[m] = -1.0f; bestp[m] = 0x7fffffff; }
    float l_np = 0.0f, l_l1 = 0.0f, l_cp = 0.0f;
    const int p0 = chunk * CH, p1e = min(p0 + CH, PP);

    for (int p = p0 + tid; p < p1e; p += ABLK) {
        float4 pr = pri4[p];
        float hw = pr.z * 0.5f, hh = pr.w * 0.5f;
        float px1 = pr.x - hw, py1 = pr.y - hh;
        float px2 = pr.x + hw, py2 = pr.y + hh;
        float area_b = (px2 - px1) * (py2 - py1);
        float bov = -1.0f; int bm = 0;
#pragma unroll
        for (int m = 0; m < MM; m++) {
            float dx = fminf(s_bx2[m], px2) - fmaxf(s_bx1[m], px1);
            float dy = fminf(s_by2[m], py2) - fmaxf(s_by1[m], py1);
            dx = fmaxf(dx, 0.0f); dy = fmaxf(dy, 0.0f);
            float inter = dx * dy;
            float den = s_area[m] + area_b - inter;
            float iou = inter * fast_rcp(den);
            if (iou > bov) { bov = iou; bm = m; }            // first-max over m
            if (iou > bestv[m]) { bestv[m] = iou; bestp[m] = p; } // first-max over p
        }
        float2 sc = sc2[p];
        float lse = lse2(sc.x, sc.y);
        bool pos = (bov >= 0.5f) && (s_lab[bm] != 0);
        pk[p]  = (unsigned char)((pos ? 16u : 0u) | (unsigned)bm);
        cer[p] = pos ? 0.0f : fmaxf(lse - sc.x, 0.0f);
        if (pos) {
            l_np += 1.0f;
            l_cp += lse - sc.y;
            float4 pl = loc4[p];
            float tx = (s_bcx[bm] - pr.x) * 10.0f / pr.z;
            float ty = (s_bcy[bm] - pr.y) * 10.0f / pr.w;
            float tw = logf(s_bw[bm] / pr.z) * 5.0f;
            float th = logf(s_bh[bm] / pr.w) * 5.0f;
            l_l1 += fabsf(pl.x - tx) + fabsf(pl.y - ty) + fabsf(pl.z - tw) + fabsf(pl.w - th);
        }
    }

    // per-object argmax: pack (valbits, 0x7fffffff-p) so u64-max == (max val, min p)
#pragma unroll
    for (int m = 0; m < MM; m++) {
        unsigned long long key =
            ((unsigned long long)__float_as_uint(bestv[m]) << 32) |
            (unsigned)(0x7fffffff - bestp[m]);
#pragma unroll
        for (int off = 32; off; off >>= 1) {
            unsigned long long o = __shfl_down(key, off);
            if (o > key) key = o;
        }
        if (lane == 0) s_pk[wav * MM + m] = key;
    }
#pragma unroll
    for (int off = 32; off; off >>= 1) {
        l_np += __shfl_down(l_np, off);
        l_l1 += __shfl_down(l_l1, off);
        l_cp += __shfl_down(l_cp, off);
    }
    if (lane == 0) { s_rf[wav * 3] = l_np; s_rf[wav * 3 + 1] = l_l1; s_rf[wav * 3 + 2] = l_cp; }
    __syncthreads();
    if (tid < MM) {
        unsigned long long key = s_pk[tid];
        for (int w = 1; w < 4; w++) {
            unsigned long long o = s_pk[w * MM + tid];
            if (o > key) key = o;
        }
        partials[((size_t)row * MM + tid) * SPLIT + chunk] = key;
    }
    if (tid == 0) {
        float np = 0, l1 = 0, cp = 0;
        for (int w = 0; w < 4; w++) { np += s_rf[w * 3]; l1 += s_rf[w * 3 + 1]; cp += s_rf[w * 3 + 2]; }
        float* cs = cstats + ((size_t)row * SPLIT + chunk) * 3;
        cs[0] = np; cs[1] = l1; cs[2] = cp;
    }
}

// ---------------- Kernel B: force prologue + register-resident top-K select ----------------
#define CBLK 1024
#define EPT 9   // ceil(PP / CBLK)
__global__ __launch_bounds__(CBLK) void mbox_sel(
    const float* __restrict__ locs, const float* __restrict__ scores,
    const float* __restrict__ boxes, const int* __restrict__ labels,
    const float* __restrict__ priors,
    const unsigned char* __restrict__ pk8, const float* __restrict__ ce0,
    const unsigned long long* __restrict__ partials,
    const float* __restrict__ cstats, float* __restrict__ rstats)
{
    const int row = blockIdx.x, tid = threadIdx.x, lane = tid & 63, wav = tid >> 6;
    __shared__ float s_bcx[MM], s_bcy[MM], s_bw[MM], s_bh[MM];
    __shared__ int s_lab[MM], s_pfo[MM], s_fp[MM];
    __shared__ float s_fv[MM], s_sum[3];
    __shared__ unsigned int s_cnt[16][4];   // per-round candidate counts (pre-zeroed)
    __shared__ unsigned int s_K;
    __shared__ float s_redf[16];
    __shared__ int s_redi[16];

    if (tid < 64) ((unsigned int*)s_cnt)[tid] = 0u;
    if (tid < MM) {
        s_fp[tid] = -1;
        const float* b = boxes + ((size_t)row * MM + tid) * 4;
        float x1 = b[0], y1 = b[1], x2 = b[2], y2 = b[3];
        s_bcx[tid] = (x1 + x2) * 0.5f; s_bcy[tid] = (y1 + y2) * 0.5f;
        s_bw[tid] = x2 - x1; s_bh[tid] = y2 - y1;
        s_lab[tid] = labels[row * MM + tid];
        const unsigned long long* pr = partials + ((size_t)row * MM + tid) * SPLIT;
        unsigned long long key = pr[0];
        for (int c = 1; c < SPLIT; c++) { unsigned long long o = pr[c]; if (o > key) key = o; }
        s_pfo[tid] = 0x7fffffff - (int)(unsigned)(key & 0xffffffffull);
    }
    if (tid >= 16 && tid < 19) {
        int j = tid - 16; float s = 0;
        for (int c = 0; c < SPLIT; c++) s += cstats[((size_t)row * SPLIT + c) * 3 + j];
        s_sum[j] = s;
    }
    __syncthreads();

    // force deltas (sequential last-wins == group by prior, keep largest m)
    float d_np = 0, d_l1 = 0, d_cp = 0;
    if (tid < MM) {
        int p = s_pfo[tid];
        bool is_last = true;
        for (int mm = tid + 1; mm < MM; mm++) if (s_pfo[mm] == p) is_last = false;
        if (is_last) {
            const float4 pr = ((const float4*)priors)[p];
            const float4 pl = ((const float4*)(locs + (size_t)row * PP * 4))[p];
            const float2 sc = ((const float2*)(scores + (size_t)row * PP * 2))[p];
            float lse = lse2(sc.x, sc.y);
            unsigned int u = pk8[(size_t)row * PP + p];
            if (u & 16u) {   // remove old positive contribution
                int mo = u & 15;
                d_np -= 1.0f; d_cp -= (lse - sc.y);
                float tx = (s_bcx[mo] - pr.x) * 10.0f / pr.z;
                float ty = (s_bcy[mo] - pr.y) * 10.0f / pr.w;
                float tw = logf(s_bw[mo] / pr.z) * 5.0f;
                float th = logf(s_bh[mo] / pr.w) * 5.0f;
                d_l1 -= fabsf(pl.x - tx) + fabsf(pl.y - ty) + fabsf(pl.z - tw) + fabsf(pl.w - th);
            }
            if (s_lab[tid] != 0) {   // add forced positive (ov=1, m=tid)
                d_np += 1.0f; d_cp += (lse - sc.y);
                float tx = (s_bcx[tid] - pr.x) * 10.0f / pr.z;
                float ty = (s_bcy[tid] - pr.y) * 10.0f / pr.w;
                float tw = logf(s_bw[tid] / pr.z) * 5.0f;
                float th = logf(s_bh[tid] / pr.w) * 5.0f;
                d_l1 += fabsf(pl.x - tx) + fabsf(pl.y - ty) + fabsf(pl.z - tw) + fabsf(pl.w - th);
                s_fv[tid] = 0.0f;                        // forced positive -> ce 0
            } else {
                s_fv[tid] = fmaxf(lse - sc.x, 0.0f);     // forced but label 0 -> negative ce
            }
            s_fp[tid] = p;
        }
    }
    if (tid < 64) {  // wave-0 reduction; lanes >= 16 hold zeros
#pragma unroll
        for (int off = 32; off; off >>= 1) {
            d_np += __shfl_down(d_np, off);
            d_l1 += __shfl_down(d_l1, off);
            d_cp += __shfl_down(d_cp, off);
        }
        if (tid == 0) {
            float np = s_sum[0] + d_np;
            rstats[(size_t)row * 8 + 0] = np;
            rstats[(size_t)row * 8 + 1] = s_sum[1] + d_l1;
            rstats[(size_t)row * 8 + 2] = s_sum[2] + d_cp;
            int K = NPR * (int)(np + 0.5f);
            s_K = (K > 0) ? (unsigned)K : 0u;
        }
    }
    __syncthreads();

    // load ce bit-patterns into registers, apply forced-prior fixes
    const float* cer = ce0 + (size_t)row * PP;
    unsigned int uv[EPT];
#pragma unroll
    for (int k = 0; k < EPT; k++) {
        int p = tid + k * CBLK;
        uv[k] = (p < PP) ? __float_as_uint(cer[p]) : 0u;
    }
    for (int t = 0; t < MM; t++) {
        int fp = s_fp[t];
        if (fp >= 0) {
            unsigned int fb = __float_as_uint(s_fv[t]);
#pragma unroll
            for (int k = 0; k < EPT; k++) if (tid + k * CBLK == fp) uv[k] = fb;
        }
    }

    // greedy 2-bit binary search for the K-th largest bit pattern
    const unsigned int K = s_K;
    unsigned int T = 0u;
    if (K > 0u) {
        for (int r = 0; r < 16; r++) {
            const int b = 30 - 2 * r;
            const unsigned int T1 = T | (1u << b), T2 = T | (2u << b), T3 = T | (3u << b);
            unsigned int c1 = 0, c2 = 0, c3 = 0;
#pragma unroll
            for (int k = 0; k < EPT; k++) {
                unsigned int u = uv[k];
                c1 += (u >= T1); c2 += (u >= T2); c3 += (u >= T3);
            }
#pragma unroll
            for (int off = 32; off; off >>= 1) {
                c1 += __shfl_down(c1, off);
                c2 += __shfl_down(c2, off);
                c3 += __shfl_down(c3, off);
            }
            if (lane == 0) {
                atomicAdd(&s_cnt[r][1], c1);
                atomicAdd(&s_cnt[r][2], c2);
                atomicAdd(&s_cnt[r][3], c3);
            }
            __syncthreads();
            unsigned int C1 = s_cnt[r][1], C2 = s_cnt[r][2], C3 = s_cnt[r][3];
            if      (C3 >= K) T = T3;
            else if (C2 >= K) T = T2;
            else if (C1 >= K) T = T1;
        }
    }

    // sum strictly greater than pivot + ties * pivot
    float sgt = 0.0f; int cgt = 0;
    if (K > 0u) {
#pragma unroll
        for (int k = 0; k < EPT; k++) {
            unsigned int u = uv[k];
            if (u > T) { sgt += __uint_as_float(u); cgt++; }
        }
    }
#pragma unroll
    for (int off = 32; off; off >>= 1) {
        sgt += __shfl_down(sgt, off);
        cgt += __shfl_down(cgt, off);
    }
    if (lane == 0) { s_redf[wav] = sgt; s_redi[wav] = cgt; }
    __syncthreads();
    if (tid == 0) {
        float s = 0; int cnt = 0;
        for (int w = 0; w < 16; w++) { s += s_redf[w]; cnt += s_redi[w]; }
        float chard = (K > 0u) ? (s + (float)(int)(K - (unsigned)cnt) * __uint_as_float(T)) : 0.0f;
        rstats[(size_t)row * 8 + 4] = chard;
    }
}

// ---------------- Kernel C: final cross-row reduction ----------------
__global__ void mbox_finalize(const float* __restrict__ rstats, float* __restrict__ out) {
    int c = threadIdx.x;
    float loss = 0.0f;
    if (c < CC) {
        float np = 0, l1 = 0, cp = 0, ch = 0;
        for (int n = 0; n < NN; n++) {
            const float* s = rstats + ((size_t)(n * CC + c)) * 8;
            np += s[0]; l1 += s[1]; cp += s[2]; ch += s[4];
        }
        float loc = l1 / fmaxf(np * 4.0f, 1.0f);
        float val = (np > 0.0f) ? (cp + ch + loc) / fmaxf(np, 1.0f) : 0.0f;
        loss = val / (float)CC;
    }
#pragma unroll
    for (int off = 32; off; off >>= 1) loss += __shfl_down(loss, off);
    if (threadIdx.x == 0) out[0] = loss;
}

extern "C" void kernel_launch(void* const* d_in, const int* in_sizes, int n_in,
                              void* d_out, int out_size, void* d_ws, size_t ws_size,
                              hipStream_t stream) {
    const float* locs   = (const float*)d_in[0];
    const float* scores = (const float*)d_in[1];
    const float* boxes  = (const float*)d_in[2];
    const int*   labels = (const int*)d_in[3];
    const float* priors = (const float*)d_in[4];
    float* out = (float*)d_out;

    char* ws = (char*)d_ws;
    float* ce0                   = (float*)ws;                               // 5,588,480 B
    unsigned char* pk8           = (unsigned char*)(ws + 5588480);           // 1,397,120 B
    unsigned long long* partials = (unsigned long long*)(ws + 6985600);      //   163,840 B
    float* cstats                = (float*)(ws + 7149440);                   //    15,360 B
    float* rstats                = (float*)(ws + 7164800);                   //     5,120 B

    mbox_p1<<<ROWS * SPLIT, ABLK, 0, stream>>>(locs, scores, boxes, labels, priors,
                                               pk8, ce0, partials, cstats);
    mbox_sel<<<ROWS, CBLK, 0, stream>>>(locs, scores, boxes, labels, priors,
                                        pk8, ce0, partials, cstats, rstats);
    mbox_finalize<<<1, 64, 0, stream>>>(rstats, out);
}